// Round 13
// baseline (398.180 us; speedup 1.0000x reference)
//
#include <hip/hip_runtime.h>
#include <math.h>

#define LEAKY(v) ((v) > 0.0f ? (v) : 0.01f * (v))

typedef _Float16 v8h __attribute__((ext_vector_type(8)));
typedef float v4f __attribute__((ext_vector_type(4)));

// ================= CSR build =================
__global__ void k_count(const int* __restrict__ ei, int* __restrict__ cnt, int E) {
    int e = blockIdx.x * blockDim.x + threadIdx.x;
    if (e < E) atomicAdd(&cnt[ei[E + e]], 1);
}

// ---- 3-phase multi-block exclusive scan (coalesced) ----
__global__ __launch_bounds__(256) void k_scan1(const int* __restrict__ cnt,
                                               int* __restrict__ rowptr,
                                               int* __restrict__ bsum, int n) {
    __shared__ int s[256];
    int t = threadIdx.x, i = blockIdx.x * 256 + t;
    int v = (i < n) ? cnt[i] : 0;
    s[t] = v;
    __syncthreads();
    for (int off = 1; off < 256; off <<= 1) {
        int u = (t >= off) ? s[t - off] : 0;
        __syncthreads();
        s[t] += u;
        __syncthreads();
    }
    if (i < n) rowptr[i] = s[t] - v;
    if (t == 255) bsum[blockIdx.x] = s[255];
}

__global__ __launch_bounds__(256) void k_scan2(int* __restrict__ bsum, int nb) {
    __shared__ int s[256];
    int t = threadIdx.x;
    int v = (t < nb) ? bsum[t] : 0;
    s[t] = v;
    __syncthreads();
    for (int off = 1; off < 256; off <<= 1) {
        int u = (t >= off) ? s[t - off] : 0;
        __syncthreads();
        s[t] += u;
        __syncthreads();
    }
    if (t < nb) bsum[t] = s[t] - v;
}

// adds block base, computes dinv, AND zeroes the pooled accumulator (fused)
__global__ __launch_bounds__(256) void k_scan3(int* __restrict__ rowptr,
                                               const int* __restrict__ bsum,
                                               const int* __restrict__ cnt,
                                               float* __restrict__ dinv, int n,
                                               float* __restrict__ pooled, int npool) {
    int i = blockIdx.x * 256 + threadIdx.x;
    if (i < n) {
        rowptr[i] += bsum[blockIdx.x];
        dinv[i] = rsqrtf(1.0f + (float)cnt[i]);  // +1 self-loop
    }
    for (int j = i; j < npool; j += gridDim.x * 256) pooled[j] = 0.0f;
}

// atomicAdd directly on rowptr: after this, rowptr[d] = end(d); start(d) = rowptr[d-1].
__global__ void k_fill(const int* __restrict__ ei, const float* __restrict__ dinv,
                       int* __restrict__ rowptr, int2* __restrict__ adj, int E) {
    int e = blockIdx.x * blockDim.x + threadIdx.x;
    if (e < E) {
        int s = ei[e], d = ei[E + e];
        int pos = atomicAdd(&rowptr[d], 1);
        adj[pos] = make_int2(s, __float_as_int(dinv[s] * dinv[d]));
    }
}

// ================= W split (3 layers, one launch) + cnt zero-init (fused; stream order
// guarantees completion before k_count): fp32 [200][200] -> f16 hi/lo [208][224] T
__global__ __launch_bounds__(256) void k_splitW3(const float* __restrict__ W1,
                                                 const float* __restrict__ W2,
                                                 const float* __restrict__ W3,
                                                 _Float16* __restrict__ th0, _Float16* __restrict__ tl0,
                                                 _Float16* __restrict__ th1, _Float16* __restrict__ tl1,
                                                 _Float16* __restrict__ th2, _Float16* __restrict__ tl2,
                                                 int* __restrict__ cnt, int n) {
    int layer = blockIdx.y;
    const float* W = (layer == 0) ? W1 : (layer == 1) ? W2 : W3;
    _Float16* Wth = (layer == 0) ? th0 : (layer == 1) ? th1 : th2;
    _Float16* Wtl = (layer == 0) ? tl0 : (layer == 1) ? tl1 : tl2;
    int idx = blockIdx.x * blockDim.x + threadIdx.x;
    // fused cnt zeroing across the whole grid
    int gidx = (blockIdx.y * gridDim.x + blockIdx.x) * 256 + threadIdx.x;
    for (int j = gidx; j < n; j += gridDim.x * gridDim.y * 256) cnt[j] = 0;
    if (idx >= 224 * 208) return;
    int k = idx / 208, c = idx - k * 208;
    float v = (k < 200 && c < 200) ? W[k * 200 + c] : 0.0f;
    _Float16 hi = (_Float16)v;
    _Float16 lo = (_Float16)(v - (float)hi);
    Wth[c * 224 + k] = hi;
    Wtl[c * 224 + k] = lo;
}

// ================= layer-1 GEMM with FUSED 4-wide gather:
// T = leaky((Ahat x)@W0 + b0) @ W1.
__global__ __launch_bounds__(256, 4) void k_gemm200_mfma_l0(const float* __restrict__ x,
                                                            const float* __restrict__ dinv,
                                                            const int* __restrict__ rowptr,
                                                            const int2* __restrict__ adj,
                                                            const float* __restrict__ W0,
                                                            const float* __restrict__ b0,
                                                            const _Float16* __restrict__ Wth,
                                                            const _Float16* __restrict__ Wtl,
                                                            _Float16* __restrict__ T, int M) {
    __shared__ _Float16 Wsh[208 * 32];
    __shared__ _Float16 Wsl[208 * 32];
    __shared__ float W0s[4][200];
    __shared__ float b0s[200];
    const int tid  = threadIdx.x;
    const int lane = tid & 63;
    const int wid  = tid >> 6;
    const int quad = lane >> 4;
    const int l16  = lane & 15;
    const int rowA = blockIdx.x * 64 + wid * 16 + l16;
    const int rowAc = min(rowA, M - 1);

    // ---- fused gather4 ----
    float w0n = dinv[rowAc]; w0n *= w0n;
    float4 xv = ((const float4*)x)[rowAc];
    float4 pxv = make_float4(xv.x * w0n, xv.y * w0n, xv.z * w0n, xv.w * w0n);
    {
        int lo = rowAc ? rowptr[rowAc - 1] : 0;
        int hi = rowptr[rowAc];
        for (int j = lo; j < hi; ++j) {
            int2 cw = adj[j];
            float w = __int_as_float(cw.y);
            float4 sv = ((const float4*)x)[cw.x];
            pxv.x += sv.x * w; pxv.y += sv.y * w; pxv.z += sv.z * w; pxv.w += sv.w * w;
        }
    }

    for (int idx = tid; idx < 1000; idx += 256) {
        if (idx < 800) W0s[idx / 200][idx % 200] = W0[idx];
        else b0s[idx - 800] = b0[idx - 800];
    }
    __syncthreads();

    v4f acc[13];
#pragma unroll
    for (int t = 0; t < 13; ++t) acc[t] = 0.0f;

    for (int k0 = 0; k0 < 224; k0 += 32) {
        v8h ah, al;
        int kb = k0 + quad * 8;
        if (kb < 200) {
#pragma unroll
            for (int j = 0; j < 8; ++j) {
                int k = kb + j;
                float pv = pxv.x * W0s[0][k] + pxv.y * W0s[1][k]
                         + pxv.z * W0s[2][k] + pxv.w * W0s[3][k] + b0s[k];
                pv = LEAKY(pv);
                _Float16 h = (_Float16)pv;
                ah[j] = h;
                al[j] = (_Float16)(pv - (float)h);
            }
        } else {
#pragma unroll
            for (int j = 0; j < 8; ++j) { ah[j] = (_Float16)0.0f; al[j] = (_Float16)0.0f; }
        }
        __syncthreads();
        for (int idx = tid; idx < 832; idx += 256) {
            int nr = idx >> 2, part = idx & 3;
            *(uint4*)&Wsh[nr * 32 + part * 8] = *(const uint4*)&Wth[nr * 224 + k0 + part * 8];
            *(uint4*)&Wsl[nr * 32 + part * 8] = *(const uint4*)&Wtl[nr * 224 + k0 + part * 8];
        }
        __syncthreads();
#pragma unroll
        for (int t = 0; t < 13; ++t) {
            int nidx = (t * 16 + l16) * 32 + quad * 8;
            v8h wh = *(const v8h*)&Wsh[nidx];
            v8h wl = *(const v8h*)&Wsl[nidx];
            acc[t] = __builtin_amdgcn_mfma_f32_16x16x32_f16(ah, wh, acc[t], 0, 0, 0);
            acc[t] = __builtin_amdgcn_mfma_f32_16x16x32_f16(ah, wl, acc[t], 0, 0, 0);
            acc[t] = __builtin_amdgcn_mfma_f32_16x16x32_f16(al, wh, acc[t], 0, 0, 0);
        }
    }
    const int rb = blockIdx.x * 64 + wid * 16 + quad * 4;
#pragma unroll
    for (int t = 0; t < 13; ++t) {
        int c = t * 16 + l16;
        if (c < 200) {
#pragma unroll
            for (int e = 0; e < 4; ++e) {
                int r = rb + e;
                if (r < M) __builtin_nontemporal_store((_Float16)acc[t][e], &T[(size_t)r * 200 + c]);
            }
        }
    }
}

// ================= layers 2-3 GEMM: T = leaky(P + bprev) @ W, f16 in/out, split-f16 MFMA =================
__global__ __launch_bounds__(256, 4) void k_gemm200_mfma(const _Float16* __restrict__ P,
                                                         const float* __restrict__ bias,
                                                         const _Float16* __restrict__ Wth,
                                                         const _Float16* __restrict__ Wtl,
                                                         _Float16* __restrict__ T, int M) {
    __shared__ _Float16 Wsh[208 * 32];
    __shared__ _Float16 Wsl[208 * 32];
    const int tid  = threadIdx.x;
    const int lane = tid & 63;
    const int wid  = tid >> 6;
    const int quad = lane >> 4;
    const int l16  = lane & 15;
    const int rowA = blockIdx.x * 64 + wid * 16 + l16;
    const int rowAc = min(rowA, M - 1);
    const _Float16* Prow = P + (size_t)rowAc * 200;

    v4f acc[13];
#pragma unroll
    for (int t = 0; t < 13; ++t) acc[t] = 0.0f;

    for (int k0 = 0; k0 < 224; k0 += 32) {
        v8h ah, al;
        int kb = k0 + quad * 8;
        if (kb < 200) {
            v8h ph = *(const v8h*)(Prow + kb);
            float4 ba = *(const float4*)(bias + kb);
            float4 bb = *(const float4*)(bias + kb + 4);
            float bv[8] = {ba.x, ba.y, ba.z, ba.w, bb.x, bb.y, bb.z, bb.w};
#pragma unroll
            for (int j = 0; j < 8; ++j) {
                float av = (float)ph[j] + bv[j];
                av = LEAKY(av);
                _Float16 h = (_Float16)av;
                ah[j] = h;
                al[j] = (_Float16)(av - (float)h);
            }
        } else {
#pragma unroll
            for (int j = 0; j < 8; ++j) { ah[j] = (_Float16)0.0f; al[j] = (_Float16)0.0f; }
        }
        __syncthreads();
        for (int idx = tid; idx < 832; idx += 256) {
            int nr = idx >> 2, part = idx & 3;
            *(uint4*)&Wsh[nr * 32 + part * 8] = *(const uint4*)&Wth[nr * 224 + k0 + part * 8];
            *(uint4*)&Wsl[nr * 32 + part * 8] = *(const uint4*)&Wtl[nr * 224 + k0 + part * 8];
        }
        __syncthreads();
#pragma unroll
        for (int t = 0; t < 13; ++t) {
            int nidx = (t * 16 + l16) * 32 + quad * 8;
            v8h wh = *(const v8h*)&Wsh[nidx];
            v8h wl = *(const v8h*)&Wsl[nidx];
            acc[t] = __builtin_amdgcn_mfma_f32_16x16x32_f16(ah, wh, acc[t], 0, 0, 0);
            acc[t] = __builtin_amdgcn_mfma_f32_16x16x32_f16(ah, wl, acc[t], 0, 0, 0);
            acc[t] = __builtin_amdgcn_mfma_f32_16x16x32_f16(al, wh, acc[t], 0, 0, 0);
        }
    }
    const int rb = blockIdx.x * 64 + wid * 16 + quad * 4;
#pragma unroll
    for (int t = 0; t < 13; ++t) {
        int c = t * 16 + l16;
        if (c < 200) {
#pragma unroll
            for (int e = 0; e < 4; ++e) {
                int r = rb + e;
                if (r < M) __builtin_nontemporal_store((_Float16)acc[t][e], &T[(size_t)r * 200 + c]);
            }
        }
    }
}

// ================= propagation (200-wide) via CSR gather, f16 in, f32 accum, f16 out =================
// Output store is non-temporal: keeps the per-XCD L2 free for the random source-row reads.
__global__ __launch_bounds__(256) void k_gather200h(const _Float16* __restrict__ t,
                                                    const float* __restrict__ dinv,
                                                    const int* __restrict__ rowptr,
                                                    const int2* __restrict__ adj,
                                                    _Float16* __restrict__ p, int n) {
    int gid = blockIdx.x * blockDim.x + threadIdx.x;
    if (gid >= n * 25) return;
    int v = gid / 25, c8 = gid - v * 25;
    const v8h* tp = (const v8h*)t;
    float w0 = dinv[v]; w0 *= w0;
    v8h tv = tp[v * 25 + c8];
    float a0[8], a1[8];
#pragma unroll
    for (int i = 0; i < 8; ++i) { a0[i] = (float)tv[i] * w0; a1[i] = 0.0f; }
    int lo = v ? rowptr[v - 1] : 0;
    int hi = rowptr[v];
    int j = lo;
    for (; j + 1 < hi; j += 2) {
        int2 e0 = adj[j], e1 = adj[j + 1];
        float wa = __int_as_float(e0.y), wb = __int_as_float(e1.y);
        v8h s0 = tp[e0.x * 25 + c8];
        v8h s1 = tp[e1.x * 25 + c8];
#pragma unroll
        for (int i = 0; i < 8; ++i) {
            a0[i] += (float)s0[i] * wa;
            a1[i] += (float)s1[i] * wb;
        }
    }
    if (j < hi) {
        int2 cw = adj[j];
        float w = __int_as_float(cw.y);
        v8h sv = tp[cw.x * 25 + c8];
#pragma unroll
        for (int i = 0; i < 8; ++i) a0[i] += (float)sv[i] * w;
    }
    v8h o;
#pragma unroll
    for (int i = 0; i < 8; ++i) o[i] = (_Float16)(a0[i] + a1[i]);
    __builtin_nontemporal_store(o, &((v8h*)p)[v * 25 + c8]);
}

// ================= pooling stage 1: segmented column sums, register-accumulated, boundary-flush =================
__global__ __launch_bounds__(256) void k_poolsum(const _Float16* __restrict__ p3,
                                                 const float* __restrict__ b3,
                                                 const int* __restrict__ batch, int n,
                                                 float* __restrict__ pooled) {
    int c = threadIdx.x;
    if (c >= 200) return;
    int base = blockIdx.x * 64;
    int end = min(base + 64, n);
    float bc = b3[c];
    int gprev = batch[base];
    float s = 0.0f;
    for (int i = base; i < end; ++i) {
        int g = batch[i];                         // broadcast load
        float v = (float)p3[(size_t)i * 200 + c] + bc;
        v = LEAKY(v);
        if (g != gprev) {
            atomicAdd(&pooled[gprev * 200 + c], s);
            s = 0.0f;
            gprev = g;
        }
        s += v;
    }
    atomicAdd(&pooled[gprev * 200 + c], s);
}

// ================= pooling finish + head MLP =================
__global__ __launch_bounds__(128) void k_mlpfin(const float* __restrict__ pooled,
                                                const int* __restrict__ batch, int n_nodes,
                                                const float* __restrict__ xs,
                                                const float* __restrict__ Wl1,
                                                const float* __restrict__ bl1,
                                                const float* __restrict__ Wl2,
                                                const float* __restrict__ bl2,
                                                float* __restrict__ out) {
    __shared__ float grow[204];
    __shared__ float partial[2];
    __shared__ int sb[2];
    int g = blockIdx.x;
    int t = threadIdx.x;
    if (t == 0) {
        int lo = 0, hi = n_nodes;
        while (lo < hi) { int m = (lo + hi) >> 1; if (batch[m] < g) lo = m + 1; else hi = m; }
        sb[0] = lo;
        int lo2 = lo, hi2 = n_nodes;
        while (lo2 < hi2) { int m = (lo2 + hi2) >> 1; if (batch[m] < g + 1) lo2 = m + 1; else hi2 = m; }
        sb[1] = lo2;
    }
    __syncthreads();
    float inv = 1.0f / fmaxf((float)(sb[1] - sb[0]), 1.0f);
    for (int idx = t; idx < 200; idx += 128) grow[idx] = pooled[g * 200 + idx] * inv;
    if (t < 4) grow[200 + t] = xs[g * 4 + t];
    __syncthreads();
    float s = bl1[t];
    for (int k = 0; k < 204; ++k) s += grow[k] * Wl1[k * 128 + t];
    s = LEAKY(s);
    float hv = s * Wl2[t];
    for (int off = 32; off > 0; off >>= 1) hv += __shfl_down(hv, off, 64);
    if ((t & 63) == 0) partial[t >> 6] = hv;
    __syncthreads();
    if (t == 0) out[g] = partial[0] + partial[1] + bl2[0];
}

extern "C" void kernel_launch(void* const* d_in, const int* in_sizes, int n_in,
                              void* d_out, int out_size, void* d_ws, size_t ws_size,
                              hipStream_t stream) {
    const float* x    = (const float*)d_in[0];
    const int*   ei   = (const int*)d_in[1];
    const float* xs   = (const float*)d_in[2];
    const int*   batch= (const int*)d_in[3];
    const float* W0   = (const float*)d_in[4];
    const float* b0   = (const float*)d_in[5];
    const float* W1   = (const float*)d_in[6];
    const float* b1   = (const float*)d_in[7];
    const float* W2   = (const float*)d_in[8];
    const float* b2   = (const float*)d_in[9];
    const float* W3   = (const float*)d_in[10];
    const float* b3   = (const float*)d_in[11];
    const float* Wl1  = (const float*)d_in[12];
    const float* bl1  = (const float*)d_in[13];
    const float* Wl2  = (const float*)d_in[14];
    const float* bl2  = (const float*)d_in[15];
    float* out = (float*)d_out;

    const int N = in_sizes[0] / 4;   // 50000 nodes
    const int E = in_sizes[1] / 2;   // 400000 edges
    const int G = in_sizes[2] / 4;   // 500 graphs

    char* ws = (char*)d_ws;
    size_t off = 0;
    auto alloc = [&](size_t bytes) { void* p = ws + off; off += (bytes + 255) & ~size_t(255); return p; };
    _Float16* bufA = (_Float16*)alloc((size_t)N * 200 * sizeof(_Float16)); // GEMM outputs
    _Float16* bufB = (_Float16*)alloc((size_t)N * 200 * sizeof(_Float16)); // gather outputs
    float* dinv   = (float*)alloc((size_t)N * sizeof(float));
    float* pooled = (float*)alloc((size_t)G * 200 * sizeof(float));
    int*   cnt    = (int*)alloc((size_t)N * sizeof(int));
    int*   rowptr = (int*)alloc(((size_t)N + 1) * sizeof(int));
    int*   bsum   = (int*)alloc(256 * sizeof(int));
    int2*  adj    = (int2*)alloc((size_t)E * sizeof(int2));
    _Float16* Wth[3]; _Float16* Wtl[3];
    for (int i = 0; i < 3; ++i) {
        Wth[i] = (_Float16*)alloc(208 * 224 * sizeof(_Float16));
        Wtl[i] = (_Float16*)alloc(208 * 224 * sizeof(_Float16));
    }

    const int B = 256;
    const int nblk = (N + 255) / 256;

    // W splits (3 layers, one launch) + cnt zeroing (fused; must precede k_count)
    dim3 sg((224 * 208 + B - 1) / B, 3);
    k_splitW3<<<sg, B, 0, stream>>>(W1, W2, W3, Wth[0], Wtl[0], Wth[1], Wtl[1], Wth[2], Wtl[2],
                                    cnt, N);

    // CSR build (by destination) + norms + pooled zero-init; fill uses shifted rowptr convention
    k_count<<<(E + B - 1) / B, B, 0, stream>>>(ei, cnt, E);
    k_scan1<<<nblk, 256, 0, stream>>>(cnt, rowptr, bsum, N);
    k_scan2<<<1, 256, 0, stream>>>(bsum, nblk);
    k_scan3<<<nblk, 256, 0, stream>>>(rowptr, bsum, cnt, dinv, N, pooled, G * 200);
    k_fill<<<(E + B - 1) / B, B, 0, stream>>>(ei, dinv, rowptr, adj, E);

    const int gblocks = (N * 25 + 255) / 256;

    // layer 1: GEMM with fused 4-wide gather (A = Ahat x @ W0 + b0 synthesized in-kernel)
    k_gemm200_mfma_l0<<<(N + 63) / 64, 256, 0, stream>>>(x, dinv, rowptr, adj, W0, b0,
                                                         Wth[0], Wtl[0], bufA, N);
    k_gather200h<<<gblocks, 256, 0, stream>>>(bufA, dinv, rowptr, adj, bufB, N);

    // layers 2-3
    k_gemm200_mfma<<<(N + 63) / 64, 256, 0, stream>>>(bufB, b1, Wth[1], Wtl[1], bufA, N);
    k_gather200h<<<gblocks, 256, 0, stream>>>(bufA, dinv, rowptr, adj, bufB, N);
    k_gemm200_mfma<<<(N + 63) / 64, 256, 0, stream>>>(bufB, b2, Wth[2], Wtl[2], bufA, N);
    k_gather200h<<<gblocks, 256, 0, stream>>>(bufA, dinv, rowptr, adj, bufB, N);

    // pooling: register-accumulated segmented sums + finish/MLP
    k_poolsum<<<(N + 63) / 64, 256, 0, stream>>>(bufB, b3, batch, N, pooled);
    k_mlpfin<<<G, 128, 0, stream>>>(pooled, batch, N, xs, Wl1, bl1, Wl2, bl2, out);
}

// Round 14
// 360.523 us; speedup vs baseline: 1.1045x; 1.1045x over previous
//
#include <hip/hip_runtime.h>
#include <math.h>

#define LEAKY(v) ((v) > 0.0f ? (v) : 0.01f * (v))

typedef _Float16 v8h __attribute__((ext_vector_type(8)));
typedef float v4f __attribute__((ext_vector_type(4)));

// ================= CSR build =================
__global__ void k_count(const int* __restrict__ ei, int* __restrict__ cnt, int E) {
    int e = blockIdx.x * blockDim.x + threadIdx.x;
    if (e < E) atomicAdd(&cnt[ei[E + e]], 1);
}

// ---- 3-phase multi-block exclusive scan (coalesced) ----
__global__ __launch_bounds__(256) void k_scan1(const int* __restrict__ cnt,
                                               int* __restrict__ rowptr,
                                               int* __restrict__ bsum, int n) {
    __shared__ int s[256];
    int t = threadIdx.x, i = blockIdx.x * 256 + t;
    int v = (i < n) ? cnt[i] : 0;
    s[t] = v;
    __syncthreads();
    for (int off = 1; off < 256; off <<= 1) {
        int u = (t >= off) ? s[t - off] : 0;
        __syncthreads();
        s[t] += u;
        __syncthreads();
    }
    if (i < n) rowptr[i] = s[t] - v;
    if (t == 255) bsum[blockIdx.x] = s[255];
}

__global__ __launch_bounds__(256) void k_scan2(int* __restrict__ bsum, int nb) {
    __shared__ int s[256];
    int t = threadIdx.x;
    int v = (t < nb) ? bsum[t] : 0;
    s[t] = v;
    __syncthreads();
    for (int off = 1; off < 256; off <<= 1) {
        int u = (t >= off) ? s[t - off] : 0;
        __syncthreads();
        s[t] += u;
        __syncthreads();
    }
    if (t < nb) bsum[t] = s[t] - v;
}

// adds block base, computes dinv, AND zeroes the pooled accumulator (fused)
__global__ __launch_bounds__(256) void k_scan3(int* __restrict__ rowptr,
                                               const int* __restrict__ bsum,
                                               const int* __restrict__ cnt,
                                               float* __restrict__ dinv, int n,
                                               float* __restrict__ pooled, int npool) {
    int i = blockIdx.x * 256 + threadIdx.x;
    if (i < n) {
        rowptr[i] += bsum[blockIdx.x];
        dinv[i] = rsqrtf(1.0f + (float)cnt[i]);  // +1 self-loop
    }
    for (int j = i; j < npool; j += gridDim.x * 256) pooled[j] = 0.0f;
}

// atomicAdd directly on rowptr: after this, rowptr[d] = end(d); start(d) = rowptr[d-1].
__global__ void k_fill(const int* __restrict__ ei, const float* __restrict__ dinv,
                       int* __restrict__ rowptr, int2* __restrict__ adj, int E) {
    int e = blockIdx.x * blockDim.x + threadIdx.x;
    if (e < E) {
        int s = ei[e], d = ei[E + e];
        int pos = atomicAdd(&rowptr[d], 1);
        adj[pos] = make_int2(s, __float_as_int(dinv[s] * dinv[d]));
    }
}

// ================= W split (3 layers, one launch) + cnt zero-init (fused; stream order
// guarantees completion before k_count): fp32 [200][200] -> f16 hi/lo [208][224] T
__global__ __launch_bounds__(256) void k_splitW3(const float* __restrict__ W1,
                                                 const float* __restrict__ W2,
                                                 const float* __restrict__ W3,
                                                 _Float16* __restrict__ th0, _Float16* __restrict__ tl0,
                                                 _Float16* __restrict__ th1, _Float16* __restrict__ tl1,
                                                 _Float16* __restrict__ th2, _Float16* __restrict__ tl2,
                                                 int* __restrict__ cnt, int n) {
    int layer = blockIdx.y;
    const float* W = (layer == 0) ? W1 : (layer == 1) ? W2 : W3;
    _Float16* Wth = (layer == 0) ? th0 : (layer == 1) ? th1 : th2;
    _Float16* Wtl = (layer == 0) ? tl0 : (layer == 1) ? tl1 : tl2;
    int idx = blockIdx.x * blockDim.x + threadIdx.x;
    // fused cnt zeroing across the whole grid
    int gidx = (blockIdx.y * gridDim.x + blockIdx.x) * 256 + threadIdx.x;
    for (int j = gidx; j < n; j += gridDim.x * gridDim.y * 256) cnt[j] = 0;
    if (idx >= 224 * 208) return;
    int k = idx / 208, c = idx - k * 208;
    float v = (k < 200 && c < 200) ? W[k * 200 + c] : 0.0f;
    _Float16 hi = (_Float16)v;
    _Float16 lo = (_Float16)(v - (float)hi);
    Wth[c * 224 + k] = hi;
    Wtl[c * 224 + k] = lo;
}

// ================= layer-1 GEMM with FUSED 4-wide gather:
// T = leaky((Ahat x)@W0 + b0) @ W1.
__global__ __launch_bounds__(256, 4) void k_gemm200_mfma_l0(const float* __restrict__ x,
                                                            const float* __restrict__ dinv,
                                                            const int* __restrict__ rowptr,
                                                            const int2* __restrict__ adj,
                                                            const float* __restrict__ W0,
                                                            const float* __restrict__ b0,
                                                            const _Float16* __restrict__ Wth,
                                                            const _Float16* __restrict__ Wtl,
                                                            _Float16* __restrict__ T, int M) {
    __shared__ _Float16 Wsh[208 * 32];
    __shared__ _Float16 Wsl[208 * 32];
    __shared__ float W0s[4][200];
    __shared__ float b0s[200];
    const int tid  = threadIdx.x;
    const int lane = tid & 63;
    const int wid  = tid >> 6;
    const int quad = lane >> 4;
    const int l16  = lane & 15;
    const int rowA = blockIdx.x * 64 + wid * 16 + l16;
    const int rowAc = min(rowA, M - 1);

    // ---- fused gather4 ----
    float w0n = dinv[rowAc]; w0n *= w0n;
    float4 xv = ((const float4*)x)[rowAc];
    float4 pxv = make_float4(xv.x * w0n, xv.y * w0n, xv.z * w0n, xv.w * w0n);
    {
        int lo = rowAc ? rowptr[rowAc - 1] : 0;
        int hi = rowptr[rowAc];
        for (int j = lo; j < hi; ++j) {
            int2 cw = adj[j];
            float w = __int_as_float(cw.y);
            float4 sv = ((const float4*)x)[cw.x];
            pxv.x += sv.x * w; pxv.y += sv.y * w; pxv.z += sv.z * w; pxv.w += sv.w * w;
        }
    }

    for (int idx = tid; idx < 1000; idx += 256) {
        if (idx < 800) W0s[idx / 200][idx % 200] = W0[idx];
        else b0s[idx - 800] = b0[idx - 800];
    }
    __syncthreads();

    v4f acc[13];
#pragma unroll
    for (int t = 0; t < 13; ++t) acc[t] = 0.0f;

    for (int k0 = 0; k0 < 224; k0 += 32) {
        v8h ah, al;
        int kb = k0 + quad * 8;
        if (kb < 200) {
#pragma unroll
            for (int j = 0; j < 8; ++j) {
                int k = kb + j;
                float pv = pxv.x * W0s[0][k] + pxv.y * W0s[1][k]
                         + pxv.z * W0s[2][k] + pxv.w * W0s[3][k] + b0s[k];
                pv = LEAKY(pv);
                _Float16 h = (_Float16)pv;
                ah[j] = h;
                al[j] = (_Float16)(pv - (float)h);
            }
        } else {
#pragma unroll
            for (int j = 0; j < 8; ++j) { ah[j] = (_Float16)0.0f; al[j] = (_Float16)0.0f; }
        }
        __syncthreads();
        for (int idx = tid; idx < 832; idx += 256) {
            int nr = idx >> 2, part = idx & 3;
            *(uint4*)&Wsh[nr * 32 + part * 8] = *(const uint4*)&Wth[nr * 224 + k0 + part * 8];
            *(uint4*)&Wsl[nr * 32 + part * 8] = *(const uint4*)&Wtl[nr * 224 + k0 + part * 8];
        }
        __syncthreads();
#pragma unroll
        for (int t = 0; t < 13; ++t) {
            int nidx = (t * 16 + l16) * 32 + quad * 8;
            v8h wh = *(const v8h*)&Wsh[nidx];
            v8h wl = *(const v8h*)&Wsl[nidx];
            acc[t] = __builtin_amdgcn_mfma_f32_16x16x32_f16(ah, wh, acc[t], 0, 0, 0);
            acc[t] = __builtin_amdgcn_mfma_f32_16x16x32_f16(ah, wl, acc[t], 0, 0, 0);
            acc[t] = __builtin_amdgcn_mfma_f32_16x16x32_f16(al, wh, acc[t], 0, 0, 0);
        }
    }
    const int rb = blockIdx.x * 64 + wid * 16 + quad * 4;
#pragma unroll
    for (int t = 0; t < 13; ++t) {
        int c = t * 16 + l16;
        if (c < 200) {
#pragma unroll
            for (int e = 0; e < 4; ++e) {
                int r = rb + e;
                if (r < M) T[(size_t)r * 200 + c] = (_Float16)acc[t][e];
            }
        }
    }
}

// ================= layers 2-3 GEMM: T = leaky(P + bprev) @ W, f16 in/out, split-f16 MFMA =================
__global__ __launch_bounds__(256, 4) void k_gemm200_mfma(const _Float16* __restrict__ P,
                                                         const float* __restrict__ bias,
                                                         const _Float16* __restrict__ Wth,
                                                         const _Float16* __restrict__ Wtl,
                                                         _Float16* __restrict__ T, int M) {
    __shared__ _Float16 Wsh[208 * 32];
    __shared__ _Float16 Wsl[208 * 32];
    const int tid  = threadIdx.x;
    const int lane = tid & 63;
    const int wid  = tid >> 6;
    const int quad = lane >> 4;
    const int l16  = lane & 15;
    const int rowA = blockIdx.x * 64 + wid * 16 + l16;
    const int rowAc = min(rowA, M - 1);
    const _Float16* Prow = P + (size_t)rowAc * 200;

    v4f acc[13];
#pragma unroll
    for (int t = 0; t < 13; ++t) acc[t] = 0.0f;

    for (int k0 = 0; k0 < 224; k0 += 32) {
        v8h ah, al;
        int kb = k0 + quad * 8;
        if (kb < 200) {
            v8h ph = *(const v8h*)(Prow + kb);
            float4 ba = *(const float4*)(bias + kb);
            float4 bb = *(const float4*)(bias + kb + 4);
            float bv[8] = {ba.x, ba.y, ba.z, ba.w, bb.x, bb.y, bb.z, bb.w};
#pragma unroll
            for (int j = 0; j < 8; ++j) {
                float av = (float)ph[j] + bv[j];
                av = LEAKY(av);
                _Float16 h = (_Float16)av;
                ah[j] = h;
                al[j] = (_Float16)(av - (float)h);
            }
        } else {
#pragma unroll
            for (int j = 0; j < 8; ++j) { ah[j] = (_Float16)0.0f; al[j] = (_Float16)0.0f; }
        }
        __syncthreads();
        for (int idx = tid; idx < 832; idx += 256) {
            int nr = idx >> 2, part = idx & 3;
            *(uint4*)&Wsh[nr * 32 + part * 8] = *(const uint4*)&Wth[nr * 224 + k0 + part * 8];
            *(uint4*)&Wsl[nr * 32 + part * 8] = *(const uint4*)&Wtl[nr * 224 + k0 + part * 8];
        }
        __syncthreads();
#pragma unroll
        for (int t = 0; t < 13; ++t) {
            int nidx = (t * 16 + l16) * 32 + quad * 8;
            v8h wh = *(const v8h*)&Wsh[nidx];
            v8h wl = *(const v8h*)&Wsl[nidx];
            acc[t] = __builtin_amdgcn_mfma_f32_16x16x32_f16(ah, wh, acc[t], 0, 0, 0);
            acc[t] = __builtin_amdgcn_mfma_f32_16x16x32_f16(ah, wl, acc[t], 0, 0, 0);
            acc[t] = __builtin_amdgcn_mfma_f32_16x16x32_f16(al, wh, acc[t], 0, 0, 0);
        }
    }
    const int rb = blockIdx.x * 64 + wid * 16 + quad * 4;
#pragma unroll
    for (int t = 0; t < 13; ++t) {
        int c = t * 16 + l16;
        if (c < 200) {
#pragma unroll
            for (int e = 0; e < 4; ++e) {
                int r = rb + e;
                if (r < M) T[(size_t)r * 200 + c] = (_Float16)acc[t][e];
            }
        }
    }
}

// ================= propagation (200-wide) via CSR gather, f16 in, f32 accum, f16 out =================
__global__ __launch_bounds__(256) void k_gather200h(const _Float16* __restrict__ t,
                                                    const float* __restrict__ dinv,
                                                    const int* __restrict__ rowptr,
                                                    const int2* __restrict__ adj,
                                                    _Float16* __restrict__ p, int n) {
    int gid = blockIdx.x * blockDim.x + threadIdx.x;
    if (gid >= n * 25) return;
    int v = gid / 25, c8 = gid - v * 25;
    const v8h* tp = (const v8h*)t;
    float w0 = dinv[v]; w0 *= w0;
    v8h tv = tp[v * 25 + c8];
    float a0[8], a1[8];
#pragma unroll
    for (int i = 0; i < 8; ++i) { a0[i] = (float)tv[i] * w0; a1[i] = 0.0f; }
    int lo = v ? rowptr[v - 1] : 0;
    int hi = rowptr[v];
    int j = lo;
    for (; j + 1 < hi; j += 2) {
        int2 e0 = adj[j], e1 = adj[j + 1];
        float wa = __int_as_float(e0.y), wb = __int_as_float(e1.y);
        v8h s0 = tp[e0.x * 25 + c8];
        v8h s1 = tp[e1.x * 25 + c8];
#pragma unroll
        for (int i = 0; i < 8; ++i) {
            a0[i] += (float)s0[i] * wa;
            a1[i] += (float)s1[i] * wb;
        }
    }
    if (j < hi) {
        int2 cw = adj[j];
        float w = __int_as_float(cw.y);
        v8h sv = tp[cw.x * 25 + c8];
#pragma unroll
        for (int i = 0; i < 8; ++i) a0[i] += (float)sv[i] * w;
    }
    v8h o;
#pragma unroll
    for (int i = 0; i < 8; ++i) o[i] = (_Float16)(a0[i] + a1[i]);
    ((v8h*)p)[v * 25 + c8] = o;
}

// ================= pooling stage 1: segmented column sums, register-accumulated, boundary-flush =================
__global__ __launch_bounds__(256) void k_poolsum(const _Float16* __restrict__ p3,
                                                 const float* __restrict__ b3,
                                                 const int* __restrict__ batch, int n,
                                                 float* __restrict__ pooled) {
    int c = threadIdx.x;
    if (c >= 200) return;
    int base = blockIdx.x * 64;
    int end = min(base + 64, n);
    float bc = b3[c];
    int gprev = batch[base];
    float s = 0.0f;
    for (int i = base; i < end; ++i) {
        int g = batch[i];                         // broadcast load
        float v = (float)p3[(size_t)i * 200 + c] + bc;
        v = LEAKY(v);
        if (g != gprev) {
            atomicAdd(&pooled[gprev * 200 + c], s);
            s = 0.0f;
            gprev = g;
        }
        s += v;
    }
    atomicAdd(&pooled[gprev * 200 + c], s);
}

// ================= pooling finish + head MLP =================
__global__ __launch_bounds__(128) void k_mlpfin(const float* __restrict__ pooled,
                                                const int* __restrict__ batch, int n_nodes,
                                                const float* __restrict__ xs,
                                                const float* __restrict__ Wl1,
                                                const float* __restrict__ bl1,
                                                const float* __restrict__ Wl2,
                                                const float* __restrict__ bl2,
                                                float* __restrict__ out) {
    __shared__ float grow[204];
    __shared__ float partial[2];
    __shared__ int sb[2];
    int g = blockIdx.x;
    int t = threadIdx.x;
    if (t == 0) {
        int lo = 0, hi = n_nodes;
        while (lo < hi) { int m = (lo + hi) >> 1; if (batch[m] < g) lo = m + 1; else hi = m; }
        sb[0] = lo;
        int lo2 = lo, hi2 = n_nodes;
        while (lo2 < hi2) { int m = (lo2 + hi2) >> 1; if (batch[m] < g + 1) lo2 = m + 1; else hi2 = m; }
        sb[1] = lo2;
    }
    __syncthreads();
    float inv = 1.0f / fmaxf((float)(sb[1] - sb[0]), 1.0f);
    for (int idx = t; idx < 200; idx += 128) grow[idx] = pooled[g * 200 + idx] * inv;
    if (t < 4) grow[200 + t] = xs[g * 4 + t];
    __syncthreads();
    float s = bl1[t];
    for (int k = 0; k < 204; ++k) s += grow[k] * Wl1[k * 128 + t];
    s = LEAKY(s);
    float hv = s * Wl2[t];
    for (int off = 32; off > 0; off >>= 1) hv += __shfl_down(hv, off, 64);
    if ((t & 63) == 0) partial[t >> 6] = hv;
    __syncthreads();
    if (t == 0) out[g] = partial[0] + partial[1] + bl2[0];
}

extern "C" void kernel_launch(void* const* d_in, const int* in_sizes, int n_in,
                              void* d_out, int out_size, void* d_ws, size_t ws_size,
                              hipStream_t stream) {
    const float* x    = (const float*)d_in[0];
    const int*   ei   = (const int*)d_in[1];
    const float* xs   = (const float*)d_in[2];
    const int*   batch= (const int*)d_in[3];
    const float* W0   = (const float*)d_in[4];
    const float* b0   = (const float*)d_in[5];
    const float* W1   = (const float*)d_in[6];
    const float* b1   = (const float*)d_in[7];
    const float* W2   = (const float*)d_in[8];
    const float* b2   = (const float*)d_in[9];
    const float* W3   = (const float*)d_in[10];
    const float* b3   = (const float*)d_in[11];
    const float* Wl1  = (const float*)d_in[12];
    const float* bl1  = (const float*)d_in[13];
    const float* Wl2  = (const float*)d_in[14];
    const float* bl2  = (const float*)d_in[15];
    float* out = (float*)d_out;

    const int N = in_sizes[0] / 4;   // 50000 nodes
    const int E = in_sizes[1] / 2;   // 400000 edges
    const int G = in_sizes[2] / 4;   // 500 graphs

    char* ws = (char*)d_ws;
    size_t off = 0;
    auto alloc = [&](size_t bytes) { void* p = ws + off; off += (bytes + 255) & ~size_t(255); return p; };
    _Float16* bufA = (_Float16*)alloc((size_t)N * 200 * sizeof(_Float16)); // GEMM outputs
    _Float16* bufB = (_Float16*)alloc((size_t)N * 200 * sizeof(_Float16)); // gather outputs
    float* dinv   = (float*)alloc((size_t)N * sizeof(float));
    float* pooled = (float*)alloc((size_t)G * 200 * sizeof(float));
    int*   cnt    = (int*)alloc((size_t)N * sizeof(int));
    int*   rowptr = (int*)alloc(((size_t)N + 1) * sizeof(int));
    int*   bsum   = (int*)alloc(256 * sizeof(int));
    int2*  adj    = (int2*)alloc((size_t)E * sizeof(int2));
    _Float16* Wth[3]; _Float16* Wtl[3];
    for (int i = 0; i < 3; ++i) {
        Wth[i] = (_Float16*)alloc(208 * 224 * sizeof(_Float16));
        Wtl[i] = (_Float16*)alloc(208 * 224 * sizeof(_Float16));
    }

    const int B = 256;
    const int nblk = (N + 255) / 256;

    // W splits (3 layers, one launch) + cnt zeroing (fused; must precede k_count)
    dim3 sg((224 * 208 + B - 1) / B, 3);
    k_splitW3<<<sg, B, 0, stream>>>(W1, W2, W3, Wth[0], Wtl[0], Wth[1], Wtl[1], Wth[2], Wtl[2],
                                    cnt, N);

    // CSR build (by destination) + norms + pooled zero-init; fill uses shifted rowptr convention
    k_count<<<(E + B - 1) / B, B, 0, stream>>>(ei, cnt, E);
    k_scan1<<<nblk, 256, 0, stream>>>(cnt, rowptr, bsum, N);
    k_scan2<<<1, 256, 0, stream>>>(bsum, nblk);
    k_scan3<<<nblk, 256, 0, stream>>>(rowptr, bsum, cnt, dinv, N, pooled, G * 200);
    k_fill<<<(E + B - 1) / B, B, 0, stream>>>(ei, dinv, rowptr, adj, E);

    const int gblocks = (N * 25 + 255) / 256;

    // layer 1: GEMM with fused 4-wide gather (A = Ahat x @ W0 + b0 synthesized in-kernel)
    k_gemm200_mfma_l0<<<(N + 63) / 64, 256, 0, stream>>>(x, dinv, rowptr, adj, W0, b0,
                                                         Wth[0], Wtl[0], bufA, N);
    k_gather200h<<<gblocks, 256, 0, stream>>>(bufA, dinv, rowptr, adj, bufB, N);

    // layers 2-3
    k_gemm200_mfma<<<(N + 63) / 64, 256, 0, stream>>>(bufB, b1, Wth[1], Wtl[1], bufA, N);
    k_gather200h<<<gblocks, 256, 0, stream>>>(bufA, dinv, rowptr, adj, bufB, N);
    k_gemm200_mfma<<<(N + 63) / 64, 256, 0, stream>>>(bufB, b2, Wth[2], Wtl[2], bufA, N);
    k_gather200h<<<gblocks, 256, 0, stream>>>(bufA, dinv, rowptr, adj, bufB, N);

    // pooling: register-accumulated segmented sums + finish/MLP
    k_poolsum<<<(N + 63) / 64, 256, 0, stream>>>(bufB, b3, batch, N, pooled);
    k_mlpfin<<<G, 128, 0, stream>>>(pooled, batch, N, xs, Wl1, bl1, Wl2, bl2, out);
}